// Round 12
// baseline (184.807 us; speedup 1.0000x reference)
//
#include <hip/hip_runtime.h>
#include <math.h>

// ---- problem constants ----
// b=8, c=64, h=w=64, HEADS=4 ch=16, PATCH=32 -> windows [0,32]x[0,32] disjoint
// t=2 (cached frame + new frame), KSIZE=5 (25 taps), K=50
#define B_ 8
#define C_ 64
#define HW_ 4096

// d_out regions (floats)
#define OUT_N   2097152   // (8,64,64,64)
#define KV_N    4194304   // (8,64,2,64,64)

typedef short s4v __attribute__((ext_vector_type(4)));
typedef short s8v __attribute__((ext_vector_type(8)));
typedef float f4v __attribute__((ext_vector_type(4)));
typedef unsigned int u2v __attribute__((ext_vector_type(2)));
typedef unsigned short ushort_t;

__device__ inline unsigned short f2bf(float f) {
    unsigned int u = __builtin_bit_cast(unsigned int, f);
    u += 0x7FFFu + ((u >> 16) & 1u);      // round-to-nearest-even bf16
    return (unsigned short)(u >> 16);
}

// packed fp32->bf16x2 by byte-perm TRUNCATION (no rounding adds): a->lo, b->hi
__device__ inline unsigned int bfpack_t(float a, float b) {
    unsigned int ua = __builtin_bit_cast(unsigned int, a);
    unsigned int ub = __builtin_bit_cast(unsigned int, b);
    return __builtin_amdgcn_perm(ub, ua, 0x07060302u);
}

#define MFMA16(a, b, c) __builtin_amdgcn_mfma_f32_16x16x16bf16_1k(a, b, c, 0, 0, 0)
#define LO4(v) __builtin_shufflevector(v, v, 0, 1, 2, 3)
#define HI4(v) __builtin_shufflevector(v, v, 4, 5, 6, 7)

__global__ __launch_bounds__(256) void k0_copy(const float* __restrict__ kc,
                                               const float* __restrict__ vc,
                                               float* __restrict__ k_out,
                                               float* __restrict__ v_out) {
    int i = blockIdx.x * 256 + threadIdx.x;      // over 2 * B*C*HW
    const int n = B_ * C_ * HW_;
    int which = (i >= n);
    int j = which ? i - n : i;
    int bc = j >> 12, hw = j & 4095;
    const float* src = which ? vc : kc;
    float* dst = which ? v_out : k_out;
    dst[((size_t)bc * 2) * HW_ + hw] = src[j];   // t = 0 slot
}

// weight prep: swizzle Wf1/Wf2 into MFMA A-fragment layout (bf16).
__global__ __launch_bounds__(256) void wprep(const float* __restrict__ Wf1,
                                             const float* __restrict__ Wf2,
                                             ushort_t* __restrict__ wt1,
                                             ushort_t* __restrict__ wt2) {
    int id = blockIdx.x * 256 + threadIdx.x;   // 0..6911
    if (id >= 6912) return;
    ushort_t o[8];
    if (id < 4608) {                           // 4 ocg * 18 p * 64 lanes
        int lane = id & 63; int p = (id >> 6) % 18; int ocg = id / (18 * 64);
        int tap = p >> 1, m = p & 1;
        int oc = ocg * 16 + (lane & 15);
        int ic0 = m * 32 + (lane >> 4) * 8;
#pragma unroll
        for (int j = 0; j < 8; ++j)
            o[j] = f2bf(Wf1[((size_t)oc * 64 + ic0 + j) * 9 + tap]);
        *(uint4*)(wt1 + (size_t)id * 8) = *(uint4*)o;
    } else {
        int id2 = id - 4608;                   // 2 ocg * 18 p * 64 lanes
        int lane = id2 & 63; int p = (id2 >> 6) % 18; int ocg = id2 / (18 * 64);
        int tap = p >> 1, m = p & 1;
        int oc = ocg * 16 + (lane & 15);
        int ic0 = m * 32 + (lane >> 4) * 8;
#pragma unroll
        for (int j = 0; j < 8; ++j)
            o[j] = (oc < 25) ? f2bf(Wf2[((size_t)oc * 64 + ic0 + j) * 9 + tap]) : (ushort_t)0;
        *(uint4*)(wt2 + (size_t)id2 * 8) = *(uint4*)o;
    }
}

// 1x1 conv as MFMA GEMM: qkv[b,o<128,px] = sum_c Wqkv[o][c] x[b,c,px].
__global__ __launch_bounds__(256) void k1_mfma(const float* __restrict__ x,
                                               const float* __restrict__ Wqkv,
                                               float* __restrict__ qkv) {
    int blk = blockIdx.x;              // 1024 = 8 b * 8 otile * 16 pxblk
    int tid = threadIdx.x, lane = tid & 63, wv = tid >> 6;
    int px0 = (blk & 15) * 256 + wv * 64;
    int otile = (blk >> 4) & 7, b = blk >> 7;
    int ln15 = lane & 15, g4 = (lane >> 4) * 4;

    const float* xb = x + (size_t)b * 64 * HW_;
    s4v wf[4];
#pragma unroll
    for (int k = 0; k < 4; ++k) {
        const float* wr = Wqkv + (size_t)(otile * 16 + ln15) * 64 + k * 16 + g4;
        float4 w4 = *(const float4*)wr;
        u2v u; u.x = bfpack_t(w4.x, w4.y); u.y = bfpack_t(w4.z, w4.w);
        wf[k] = __builtin_bit_cast(s4v, u);
    }
    const f4v zf = {0.f, 0.f, 0.f, 0.f};
    f4v acc[4] = {zf, zf, zf, zf};
#pragma unroll
    for (int k = 0; k < 4; ++k) {
#pragma unroll
        for (int p = 0; p < 4; ++p) {
            const float* xp = xb + (size_t)(k * 16 + g4) * HW_ + px0 + p * 16 + ln15;
            float v0 = xp[0];
            float v1 = xp[HW_];
            float v2 = xp[2 * HW_];
            float v3 = xp[3 * HW_];
            u2v u; u.x = bfpack_t(v0, v1); u.y = bfpack_t(v2, v3);
            s4v xf = __builtin_bit_cast(s4v, u);
            acc[p] = MFMA16(wf[k], xf, acc[p]);
        }
    }
    float* ob = qkv + ((size_t)b * 128 + otile * 16) * HW_ + px0;
#pragma unroll
    for (int p = 0; p < 4; ++p)
#pragma unroll
        for (int j = 0; j < 4; ++j)
            ob[(size_t)(g4 + j) * HW_ + p * 16 + ln15] = acc[p][j];
}

// depthwise 3x3 (zero pad). q (o<64) -> qbuf ; k (64<=o<128) -> k_out/v_out t=1 slots
__global__ __launch_bounds__(256) void k2_dw(const float* __restrict__ qkv,
                                             const float* __restrict__ Wdw,
                                             float* __restrict__ qbuf,
                                             float* __restrict__ k_out,
                                             float* __restrict__ v_out) {
    int t = blockIdx.x * 256 + threadIdx.x;   // 8*128*4096
    int hw = t & 4095; int bo = t >> 12; int o = bo & 127; int b = bo >> 7;
    int y = hw >> 6, xx0 = hw & 63;
    const float* in = qkv + (size_t)bo * HW_;
    const float* w = Wdw + o * 9;
    float acc = 0.f;
#pragma unroll
    for (int dy = 0; dy < 3; ++dy) {
        int yy = y + dy - 1;
        if (yy < 0 || yy > 63) continue;
#pragma unroll
        for (int dx = 0; dx < 3; ++dx) {
            int xx = xx0 + dx - 1;
            if (xx < 0 || xx > 63) continue;
            acc = fmaf(in[yy * 64 + xx], w[dy * 3 + dx], acc);
        }
    }
    if (o < 64) {
        qbuf[((size_t)b * 64 + o) * HW_ + hw] = acc;
    } else {
        int oc = o - 64;
        size_t off = (((size_t)b * 64 + oc) * 2 + 1) * HW_ + hw;
        k_out[off] = acc;   // k_ t=1
        v_out[off] = acc;   // v_ t=1  (reference uses k, not v!)
    }
}

// MFMA implicit-GEMM conv 3x3 64->64 + LeakyReLU, bf16 in/out fp32 accum.
__global__ __launch_bounds__(256) void k3_mfma1(const float* __restrict__ k_out,
                                                const float* __restrict__ vc,
                                                const ushort_t* __restrict__ wt1,
                                                ushort_t* __restrict__ fb16) {
    int stripe = blockIdx.x;  // 0..31
    int f = blockIdx.y;       // 0..23
    int tid = threadIdx.x;
    __shared__ ushort_t ilds[4 * 66 * 72];
    const float* src; size_t icstr;
    if (f < 16) { src = k_out + (((size_t)(f >> 1) * 128) + (f & 1)) * HW_; icstr = 2 * HW_; }
    else        { src = vc + ((size_t)(f - 16) * 64) * HW_;                 icstr = HW_; }
    int y0 = stripe * 2;

    int lane = tid & 63, wv = tid >> 6, g = lane >> 4, c16 = lane & 15;
    s8v a[18];
    const ushort_t* wb = wt1 + ((size_t)wv * 18) * 512 + lane * 8;
#pragma unroll
    for (int p = 0; p < 18; ++p) a[p] = *(const s8v*)(wb + p * 512);

    {
        int rc = tid >> 5, idx = tid & 31;
        int r = rc >> 1, side = rc & 1;
        ((unsigned int*)ilds)[(r * 66 + side * 65) * 36 + idx] = 0u;
    }
    {
        int r = tid >> 6, x = tid & 63;
        int y = y0 - 1 + r;
        bool valid = (y >= 0 && y < 64);
        const float* rowp = src + y * 64 + x;
        ushort_t* dst = ilds + ((r * 66) + x + 1) * 72;
#pragma unroll
        for (int ic4 = 0; ic4 < 16; ++ic4) {
            ushort_t o[4];
#pragma unroll
            for (int j = 0; j < 4; ++j) {
                float v = valid ? rowp[(size_t)(ic4 * 4 + j) * icstr] : 0.f;
                o[j] = f2bf(v);
            }
            *(uint2*)(dst + ic4 * 4) = *(uint2*)o;
        }
    }
    __syncthreads();

#pragma unroll
    for (int r_out = 0; r_out < 2; ++r_out)
#pragma unroll
        for (int xp = 0; xp < 2; ++xp) {
            int x0 = xp * 32, x1 = x0 + 16;
            f4v acc0 = {0.f, 0.f, 0.f, 0.f}, acc1 = {0.f, 0.f, 0.f, 0.f};
#pragma unroll
            for (int tap = 0; tap < 9; ++tap) {
                const int dy = tap / 3, dx = tap % 3;
                const ushort_t* bp0 = ilds + (((r_out + dy) * 66) + x0 + c16 + dx) * 72 + g * 8;
                const ushort_t* bp1 = ilds + (((r_out + dy) * 66) + x1 + c16 + dx) * 72 + g * 8;
                s8v b00 = *(const s8v*)bp0;          // ic g*8..+7
                s8v b01 = *(const s8v*)(bp0 + 32);   // ic 32+g*8..+7
                s8v b10 = *(const s8v*)bp1;
                s8v b11 = *(const s8v*)(bp1 + 32);
                acc0 = MFMA16(LO4(a[2 * tap]),     LO4(b00), acc0);
                acc1 = MFMA16(LO4(a[2 * tap]),     LO4(b10), acc1);
                acc0 = MFMA16(HI4(a[2 * tap]),     HI4(b00), acc0);
                acc1 = MFMA16(HI4(a[2 * tap]),     HI4(b10), acc1);
                acc0 = MFMA16(LO4(a[2 * tap + 1]), LO4(b01), acc0);
                acc1 = MFMA16(LO4(a[2 * tap + 1]), LO4(b11), acc1);
                acc0 = MFMA16(HI4(a[2 * tap + 1]), HI4(b01), acc0);
                acc1 = MFMA16(HI4(a[2 * tap + 1]), HI4(b11), acc1);
            }
            int py = (y0 + r_out) * 64;
#pragma unroll
            for (int j = 0; j < 4; ++j) {
                int oc = wv * 16 + g * 4 + j;
                float v0 = acc0[j]; v0 = (v0 >= 0.f) ? v0 : 0.2f * v0;
                float v1 = acc1[j]; v1 = (v1 >= 0.f) ? v1 : 0.2f * v1;
                fb16[((size_t)f * 64 + oc) * HW_ + py + x0 + c16] = f2bf(v0);
                fb16[((size_t)f * 64 + oc) * HW_ + py + x1 + c16] = f2bf(v1);
            }
        }
}

// MFMA implicit-GEMM conv 3x3 64->25 on bf16 fbuf -> kerb fp32.
__global__ __launch_bounds__(256) void k3b_mfma2(const ushort_t* __restrict__ fb16,
                                                 const ushort_t* __restrict__ wt2,
                                                 float* __restrict__ kerb) {
    int stripe = blockIdx.x;  // 0..31
    int f = blockIdx.y;       // 0..23
    int tid = threadIdx.x;
    __shared__ ushort_t ilds[4 * 66 * 72];
    int y0 = stripe * 2;

    int lane = tid & 63, wv = tid >> 6, g = lane >> 4, c16 = lane & 15;
    int ocg = wv & 1, xh = wv >> 1;
    s8v a[18];
    const ushort_t* wb = wt2 + ((size_t)ocg * 18) * 512 + lane * 8;
#pragma unroll
    for (int p = 0; p < 18; ++p) a[p] = *(const s8v*)(wb + p * 512);

    {
        int rc = tid >> 5, idx = tid & 31;
        int r = rc >> 1, side = rc & 1;
        ((unsigned int*)ilds)[(r * 66 + side * 65) * 36 + idx] = 0u;
    }
    {
        int r = tid >> 6, x = tid & 63;
        int y = y0 - 1 + r;
        bool valid = (y >= 0 && y < 64);
        const ushort_t* rowp = fb16 + (size_t)f * 64 * HW_ + y * 64 + x;
        ushort_t* dst = ilds + ((r * 66) + x + 1) * 72;
#pragma unroll
        for (int ic4 = 0; ic4 < 16; ++ic4) {
            ushort_t o[4];
#pragma unroll
            for (int j = 0; j < 4; ++j)
                o[j] = valid ? rowp[(size_t)(ic4 * 4 + j) * HW_] : (ushort_t)0;
            *(uint2*)(dst + ic4 * 4) = *(uint2*)o;
        }
    }
    __syncthreads();

#pragma unroll
    for (int r_out = 0; r_out < 2; ++r_out) {
        int x0 = xh * 32, x1 = x0 + 16;
        f4v acc0 = {0.f, 0.f, 0.f, 0.f}, acc1 = {0.f, 0.f, 0.f, 0.f};
#pragma unroll
        for (int tap = 0; tap < 9; ++tap) {
            const int dy = tap / 3, dx = tap % 3;
            const ushort_t* bp0 = ilds + (((r_out + dy) * 66) + x0 + c16 + dx) * 72 + g * 8;
            const ushort_t* bp1 = ilds + (((r_out + dy) * 66) + x1 + c16 + dx) * 72 + g * 8;
            s8v b00 = *(const s8v*)bp0;
            s8v b01 = *(const s8v*)(bp0 + 32);
            s8v b10 = *(const s8v*)bp1;
            s8v b11 = *(const s8v*)(bp1 + 32);
            acc0 = MFMA16(LO4(a[2 * tap]),     LO4(b00), acc0);
            acc1 = MFMA16(LO4(a[2 * tap]),     LO4(b10), acc1);
            acc0 = MFMA16(HI4(a[2 * tap]),     HI4(b00), acc0);
            acc1 = MFMA16(HI4(a[2 * tap]),     HI4(b10), acc1);
            acc0 = MFMA16(LO4(a[2 * tap + 1]), LO4(b01), acc0);
            acc1 = MFMA16(LO4(a[2 * tap + 1]), LO4(b11), acc1);
            acc0 = MFMA16(HI4(a[2 * tap + 1]), HI4(b01), acc0);
            acc1 = MFMA16(HI4(a[2 * tap + 1]), HI4(b11), acc1);
        }
        int py = (y0 + r_out) * 64;
#pragma unroll
        for (int j = 0; j < 4; ++j) {
            int oc = ocg * 16 + g * 4 + j;
            if (oc < 25) {
                kerb[((size_t)f * 25 + oc) * HW_ + py + x0 + c16] = acc0[j];
                kerb[((size_t)f * 25 + oc) * HW_ + py + x1 + c16] = acc1[j];
            }
        }
    }
}

// apply 50-tap dynamic filter; kern staged + mean fused in LDS.
// Register sliding-window over px: thread (pg=tid&15 -> px4=pg*4, cg=tid>>4) owns
// 4 px x 2 ch (ch = chh*32 + cg*2 + {0,1}). Per (ti,row,ch): 3 aligned float4
// cover x[px4-4..px4+7]; taps read shifted windows -> 60 vec loads vs 400 scalars.
// FMA order per output = (ti, r, dx) == (ti, kk): bit-identical to round-10.
__global__ __launch_bounds__(256) void k4b_apply(const float* __restrict__ kerb,
                                                 const float* __restrict__ k_out,
                                                 const float* __restrict__ v_out,
                                                 float* __restrict__ kfil,
                                                 float* __restrict__ vfil) {
    int y = blockIdx.x, b = blockIdx.y;
    int p = blockIdx.z >> 1, chh = blockIdx.z & 1;
    int tid = threadIdx.x;
    __shared__ float klds[50][64];
    __shared__ float part[4][64];
    int f0 = (p == 0) ? 2 * b : 16 + b;
    int f1 = 2 * b + 1;
    // stage raw kernel taps
    for (int idx = tid; idx < 3200; idx += 256) {
        int px_ = idx & 63, j = idx >> 6;      // j in [0,50)
        int ti = (j >= 25); int kk = j - ti * 25;
        int fr = ti ? f1 : f0;
        klds[j][px_] = kerb[((size_t)fr * 25 + kk) * HW_ + y * 64 + px_];
    }
    __syncthreads();
    // fused mean over the 50 taps
    {
        int px_ = tid & 63, q_ = tid >> 6;
        int j0 = q_ * 13; int j1 = j0 + 13; if (j1 > 50) j1 = 50;
        float s = 0.f;
        for (int j = j0; j < j1; ++j) s += klds[j][px_];
        part[q_][px_] = s;
    }
    __syncthreads();
    if (tid < 64) {
        float m = (part[0][tid] + part[1][tid]) + (part[2][tid] + part[3][tid]);
        part[0][tid] = m * (1.f / 50.f);
    }
    __syncthreads();
    for (int idx = tid; idx < 3200; idx += 256) {
        int px_ = idx & 63, j = idx >> 6;
        klds[j][px_] += 0.02f - part[0][px_];
    }
    __syncthreads();

    int pg = tid & 15, cg = tid >> 4;
    int px4 = pg * 4;
    const float* xsrc = ((p == 0) ? k_out : v_out)
                      + ((size_t)b * 64 + chh * 32 + cg * 2) * 2 * HW_;
    float acc0[4] = {0.f, 0.f, 0.f, 0.f};
    float acc1[4] = {0.f, 0.f, 0.f, 0.f};
    bool ledge = (px4 == 0), redge = (px4 == 60);
    int loff = ledge ? 0 : px4 - 4;
    int roff = redge ? 60 : px4 + 4;

#pragma unroll
    for (int ti = 0; ti < 2; ++ti) {
#pragma unroll
        for (int r = 0; r < 5; ++r) {
            int cy = y + r - 2; cy = cy < 0 ? 0 : (cy > 63 ? 63 : cy);
            const float* sp0 = xsrc + (size_t)ti * HW_ + cy * 64;
            const float* sp1 = sp0 + 2 * HW_;
            float xw0[12], xw1[12];
            {
                float4 l4 = *(const float4*)(sp0 + loff);
                float4 m4 = *(const float4*)(sp0 + px4);
                float4 r4 = *(const float4*)(sp0 + roff);
                xw0[0] = l4.x; xw0[1] = l4.y;
                xw0[2] = ledge ? l4.x : l4.z;
                xw0[3] = ledge ? l4.x : l4.w;
                xw0[4] = m4.x; xw0[5] = m4.y; xw0[6] = m4.z; xw0[7] = m4.w;
                xw0[8] = redge ? r4.w : r4.x;
                xw0[9] = redge ? r4.w : r4.y;
                xw0[10] = r4.z; xw0[11] = r4.w;
            }
            {
                float4 l4 = *(const float4*)(sp1 + loff);
                float4 m4 = *(const float4*)(sp1 + px4);
                float4 r4 = *(const float4*)(sp1 + roff);
                xw1[0] = l4.x; xw1[1] = l4.y;
                xw1[2] = ledge ? l4.x : l4.z;
                xw1[3] = ledge ? l4.x : l4.w;
                xw1[4] = m4.x; xw1[5] = m4.y; xw1[6] = m4.z; xw1[7] = m4.w;
                xw1[8] = redge ? r4.w : r4.x;
                xw1[9] = redge ? r4.w : r4.y;
                xw1[10] = r4.z; xw1[11] = r4.w;
            }
#pragma unroll
            for (int dx = 0; dx < 5; ++dx) {
                float4 kv = *(const float4*)&klds[ti * 25 + r * 5 + dx][px4];
                float kva[4] = {kv.x, kv.y, kv.z, kv.w};
#pragma unroll
                for (int i = 0; i < 4; ++i) {
                    acc0[i] = fmaf(xw0[i + dx + 2], kva[i], acc0[i]);
                    acc1[i] = fmaf(xw1[i + dx + 2], kva[i], acc1[i]);
                }
            }
        }
    }
    float* ob = ((p == 0) ? kfil : vfil)
              + ((size_t)b * 64 + chh * 32 + cg * 2) * HW_ + y * 64 + px4;
    *(float4*)ob = *(float4*)acc0;
    *(float4*)(ob + HW_) = *(float4*)acc1;
}

// L2-normalize per (pixel, head) and convert to bf16 in MFMA-friendly layout:
// qbf/kbf[unit][row 0..1023][ch 0..15], unit = ((b*4+head)*4 + win)
__global__ __launch_bounds__(256) void k4c_cvt(const float* __restrict__ qbuf,
                                               const float* __restrict__ kfil,
                                               unsigned short* __restrict__ qbf,
                                               unsigned short* __restrict__ kbf) {
    int row = blockIdx.x * 256 + threadIdx.x;     // 0..1023
    int unit = blockIdx.y;                        // 128
    int which = blockIdx.z;                       // 0=q, 1=k
    int win = unit & 3, head = (unit >> 2) & 3, b = unit >> 4;
    int wy = win >> 1, wx = win & 1;
    int gpx = ((wy * 32 + (row >> 5)) << 6) + wx * 32 + (row & 31);
    const float* src = (which ? kfil : qbuf) + ((size_t)b * 64 + head * 16) * HW_ + gpx;
    float v[16]; float ss = 0.f;
#pragma unroll
    for (int i = 0; i < 16; ++i) { v[i] = src[(size_t)i * HW_]; ss = fmaf(v[i], v[i], ss); }
    float sc = 1.f / fmaxf(sqrtf(ss), 1e-12f);
    unsigned short o[16];
#pragma unroll
    for (int i = 0; i < 16; ++i) o[i] = f2bf(v[i] * sc);
    unsigned short* dst = (which ? kbf : qbf) + ((size_t)unit * 1024 + row) * 16;
    ((uint4*)dst)[0] = ((uint4*)o)[0];
    ((uint4*)dst)[1] = ((uint4*)o)[1];
}

// MFMA windowed attention (fixed-max softmax, exact since |q.k|<=~1).
// P->bf16 via perm TRUNCATION; l via ones-MFMA on the matrix pipe (numerator and
// denominator then sum the SAME truncated P -> bias cancels); exp2 via raw builtin.
__global__ __launch_bounds__(256) void k5_mfma(const unsigned short* __restrict__ qbf,
                                               const unsigned short* __restrict__ kbf,
                                               const float* __restrict__ vfil,
                                               const float* __restrict__ temp,
                                               float* __restrict__ attno) {
    int qb = blockIdx.x;          // 8
    int unit = blockIdx.y;        // 128
    int win = unit & 3, head = (unit >> 2) & 3, b = unit >> 4;
    int wy = win >> 1, wx = win & 1;
    int tid = threadIdx.x, lane = tid & 63, wv = tid >> 6;
    __shared__ unsigned short vt[16][1032];   // V^T bf16, row padded
    size_t cbase = ((size_t)b * 64 + head * 16) * HW_;

#pragma unroll
    for (int it = 0; it < 4; ++it) {
        int i = it * 256 + tid;                 // 1024 = 16 ch * 64 key-chunks
        int ch = i >> 6, k16 = (i & 63) << 4;
        int gpx = ((wy * 32 + (k16 >> 5)) << 6) + wx * 32 + (k16 & 31);
        const float* src = vfil + cbase + (size_t)ch * HW_ + gpx;
        unsigned int w[8];
#pragma unroll
        for (int j = 0; j < 8; ++j) w[j] = bfpack_t(src[2 * j], src[2 * j + 1]);
        uint4* d = (uint4*)&vt[ch][k16];
        d[0] = *(uint4*)&w[0];
        d[1] = *(uint4*)&w[4];
    }

    float tmp = temp[head];
    float a_s = tmp * 1.44269504f;
    float b_s = (fabsf(tmp) + 1e-6f) * 1.44269504f;

    int ln15 = lane & 15, g4 = (lane >> 4) * 4;
    const unsigned short* qu = qbf + (size_t)unit * 1024 * 16;
    const unsigned short* ku = kbf + (size_t)unit * 1024 * 16;
    int qt0 = qb * 8 + wv * 2;
    s4v qf0 = *(const s4v*)(qu + ((size_t)(qt0 * 16 + ln15)) * 16 + g4);
    s4v qf1 = *(const s4v*)(qu + ((size_t)((qt0 + 1) * 16 + ln15)) * 16 + g4);

    const short one_bf = (short)0x3F80;                       // bf16(1.0)
    const s4v ones = {one_bf, one_bf, one_bf, one_bf};
    const f4v zf = {0.f, 0.f, 0.f, 0.f};
    f4v o0 = zf, o1 = zf, lacc0 = zf, lacc1 = zf;

    __syncthreads();
    for (int tb = 0; tb < 64; ++tb) {
        s4v kf = *(const s4v*)(ku + ((size_t)(tb * 16 + ln15)) * 16 + g4);
        s4v vf = *(const s4v*)(&vt[ln15][tb * 16 + g4]);
        f4v s0 = MFMA16(kf, qf0, zf);
        f4v s1 = MFMA16(kf, qf1, zf);
        float p00 = __builtin_amdgcn_exp2f(fmaf(s0[0], a_s, -b_s));
        float p01 = __builtin_amdgcn_exp2f(fmaf(s0[1], a_s, -b_s));
        float p02 = __builtin_amdgcn_exp2f(fmaf(s0[2], a_s, -b_s));
        float p03 = __builtin_amdgcn_exp2f(fmaf(s0[3], a_s, -b_s));
        float p10 = __builtin_amdgcn_exp2f(fmaf(s1[0], a_s, -b_s));
        float p11 = __builtin_amdgcn_exp2f(fmaf(s1[1], a_s, -b_s));
        float p12 = __builtin_amdgcn_exp2f(fmaf(s1[2], a_s, -b_s));
        float p13 = __builtin_amdgcn_exp2f(fmaf(s1[3], a_s, -b_s));
        u2v u0; u0.x = bfpack_t(p00, p01); u0.y = bfpack_t(p02, p03);
        u2v u1; u1.x = bfpack_t(p10, p11); u1.y = bfpack_t(p12, p13);
        s4v pf0 = __builtin_bit_cast(s4v, u0);
        s4v pf1 = __builtin_bit_cast(s4v, u1);
        o0 = MFMA16(vf, pf0, o0);
        o1 = MFMA16(vf, pf1, o1);
        lacc0 = MFMA16(ones, pf0, lacc0);     // row-sums on the matrix pipe
        lacc1 = MFMA16(ones, pf1, lacc1);
    }

    float inv0 = 1.f / lacc0[0], inv1 = 1.f / lacc1[0];

    int q0 = qt0 * 16 + ln15;
    int q1 = q0 + 16;
    int gq0 = ((wy * 32 + (q0 >> 5)) << 6) + wx * 32 + (q0 & 31);
    int gq1 = ((wy * 32 + (q1 >> 5)) << 6) + wx * 32 + (q1 & 31);
#pragma unroll
    for (int j = 0; j < 4; ++j) {
        attno[cbase + (size_t)(g4 + j) * HW_ + gq0] = o0[j] * inv0;
        attno[cbase + (size_t)(g4 + j) * HW_ + gq1] = o1[j] * inv1;
    }
}

// 1x1 proj as MFMA GEMM: out[b,o,px] = sum_c Wp[o][c] attno[b,c,px].
__global__ __launch_bounds__(256) void k6_mfma(const float* __restrict__ attno,
                                               const float* __restrict__ Wp,
                                               float* __restrict__ out) {
    int blk = blockIdx.x;              // 512 = 8 b * 4 otile * 16 pxblk
    int tid = threadIdx.x, lane = tid & 63, wv = tid >> 6;
    int px0 = (blk & 15) * 256 + wv * 64;
    int otile = (blk >> 4) & 3, b = blk >> 6;
    int ln15 = lane & 15, g4 = (lane >> 4) * 4;

    const float* ab = attno + (size_t)b * 64 * HW_;
    s4v wf[4];
#pragma unroll
    for (int k = 0; k < 4; ++k) {
        const float* wr = Wp + (size_t)(otile * 16 + ln15) * 64 + k * 16 + g4;
        float4 w4 = *(const float4*)wr;
        u2v u; u.x = bfpack_t(w4.x, w4.y); u.y = bfpack_t(w4.z, w4.w);
        wf[k] = __builtin_bit_cast(s4v, u);
    }
    const f4v zf = {0.f, 0.f, 0.f, 0.f};
    f4v acc[4] = {zf, zf, zf, zf};
#pragma unroll
    for (int k = 0; k < 4; ++k) {
#pragma unroll
        for (int p = 0; p < 4; ++p) {
            const float* xp = ab + (size_t)(k * 16 + g4) * HW_ + px0 + p * 16 + ln15;
            float v0 = xp[0];
            float v1 = xp[HW_];
            float v2 = xp[2 * HW_];
            float v3 = xp[3 * HW_];
            u2v u; u.x = bfpack_t(v0, v1); u.y = bfpack_t(v2, v3);
            s4v xf = __builtin_bit_cast(s4v, u);
            acc[p] = MFMA16(wf[k], xf, acc[p]);
        }
    }
    float* ob = out + ((size_t)b * 64 + otile * 16) * HW_ + px0;
#pragma unroll
    for (int p = 0; p < 4; ++p)
#pragma unroll
        for (int j = 0; j < 4; ++j)
            ob[(size_t)(g4 + j) * HW_ + p * 16 + ln15] = acc[p][j];
}

extern "C" void kernel_launch(void* const* d_in, const int* in_sizes, int n_in,
                              void* d_out, int out_size, void* d_ws, size_t ws_size,
                              hipStream_t stream) {
    const float* x    = (const float*)d_in[0];
    const float* kc   = (const float*)d_in[1];
    const float* vc   = (const float*)d_in[2];
    const float* Wqkv = (const float*)d_in[3];
    const float* Wdw  = (const float*)d_in[4];
    const float* Wf1  = (const float*)d_in[5];
    const float* Wf2  = (const float*)d_in[6];
    const float* Wpr  = (const float*)d_in[7];
    const float* temp = (const float*)d_in[8];

    float* out   = (float*)d_out;
    float* k_out = out + OUT_N;            // (8,64,2,64,64)
    float* v_out = out + OUT_N + KV_N;

    float* ws   = (float*)d_ws;
    float* qkv  = ws;                      // [0 .. 4.19M floats) — dead after k2
    unsigned short* fb16 = (unsigned short*)ws;            // 6.29M shorts (reuses qkv region after k2)
    unsigned short* qbf = (unsigned short*)ws;             // 2M shorts (after fb16 dead)
    unsigned short* kbf = (unsigned short*)(ws + 1048576); // 2M shorts
    float* qbuf = ws + 6291456;            // 2,097,152
    float* kerb = ws + 8388608;            // 2,457,600
    float* kfil = ws + 10846208;           // 2,097,152
    float* vfil = ws + 12943360;           // 2,097,152
    unsigned short* wt1 = (unsigned short*)(ws + 15106048); // 36864 shorts
    unsigned short* wt2 = wt1 + 36864;                      // 18432 shorts
    float* attno= kerb;                    // alias: kerb free after k4b

    wprep   <<<27,    256, 0, stream>>>(Wf1, Wf2, wt1, wt2);
    k0_copy <<<16384, 256, 0, stream>>>(kc, vc, k_out, v_out);
    k1_mfma <<<1024,  256, 0, stream>>>(x, Wqkv, qkv);
    k2_dw   <<<16384, 256, 0, stream>>>(qkv, Wdw, qbuf, k_out, v_out);
    k3_mfma1<<<dim3(32, 24), 256, 0, stream>>>(k_out, vc, wt1, fb16);
    k3b_mfma2<<<dim3(32, 24), 256, 0, stream>>>(fb16, wt2, kerb);
    k4b_apply<<<dim3(64, 8, 4), 256, 0, stream>>>(kerb, k_out, v_out, kfil, vfil);
    k4c_cvt <<<dim3(4, 128, 2), 256, 0, stream>>>(qbuf, kfil, qbf, kbf);
    k5_mfma <<<dim3(8, 128), 256, 0, stream>>>(qbf, kbf, vfil, temp, attno);
    k6_mfma <<<512,   256, 0, stream>>>(attno, Wpr, out);
}

// Round 13
// 181.994 us; speedup vs baseline: 1.0155x; 1.0155x over previous
//
#include <hip/hip_runtime.h>
#include <math.h>

// ---- problem constants ----
// b=8, c=64, h=w=64, HEADS=4 ch=16, PATCH=32 -> windows [0,32]x[0,32] disjoint
// t=2 (cached frame + new frame), KSIZE=5 (25 taps), K=50
#define B_ 8
#define C_ 64
#define HW_ 4096

// d_out regions (floats)
#define OUT_N   2097152   // (8,64,64,64)
#define KV_N    4194304   // (8,64,2,64,64)

typedef short s4v __attribute__((ext_vector_type(4)));
typedef short s8v __attribute__((ext_vector_type(8)));
typedef float f4v __attribute__((ext_vector_type(4)));
typedef unsigned int u2v __attribute__((ext_vector_type(2)));
typedef unsigned short ushort_t;

__device__ inline unsigned short f2bf(float f) {
    unsigned int u = __builtin_bit_cast(unsigned int, f);
    u += 0x7FFFu + ((u >> 16) & 1u);      // round-to-nearest-even bf16
    return (unsigned short)(u >> 16);
}

// packed fp32->bf16x2 by byte-perm TRUNCATION (no rounding adds): a->lo, b->hi
__device__ inline unsigned int bfpack_t(float a, float b) {
    unsigned int ua = __builtin_bit_cast(unsigned int, a);
    unsigned int ub = __builtin_bit_cast(unsigned int, b);
    return __builtin_amdgcn_perm(ub, ua, 0x07060302u);
}

#define MFMA16(a, b, c) __builtin_amdgcn_mfma_f32_16x16x16bf16_1k(a, b, c, 0, 0, 0)
#define LO4(v) __builtin_shufflevector(v, v, 0, 1, 2, 3)
#define HI4(v) __builtin_shufflevector(v, v, 4, 5, 6, 7)

// float4 cache->output copy: 4096 blocks cover 2 * (B*C*HW/4) float4s
__global__ __launch_bounds__(256) void k0_copy(const float4* __restrict__ kc,
                                               const float4* __restrict__ vc,
                                               float* __restrict__ k_out,
                                               float* __restrict__ v_out) {
    int i = blockIdx.x * 256 + threadIdx.x;
    const int n4 = (B_ * C_ * HW_) / 4;
    int which = (i >= n4);
    int j = which ? i - n4 : i;
    const float4* src = which ? vc : kc;
    float4 v = src[j];
    int bc = j >> 10, hw4 = j & 1023;        // 1024 float4 per (b,c)
    float* dst = (which ? v_out : k_out) + ((size_t)bc * 2) * HW_ + hw4 * 4;
    *(float4*)dst = v;                        // t = 0 slot
}

// weight prep: swizzle Wf1/Wf2 into MFMA A-fragment layout (bf16).
__global__ __launch_bounds__(256) void wprep(const float* __restrict__ Wf1,
                                             const float* __restrict__ Wf2,
                                             ushort_t* __restrict__ wt1,
                                             ushort_t* __restrict__ wt2) {
    int id = blockIdx.x * 256 + threadIdx.x;   // 0..6911
    if (id >= 6912) return;
    ushort_t o[8];
    if (id < 4608) {                           // 4 ocg * 18 p * 64 lanes
        int lane = id & 63; int p = (id >> 6) % 18; int ocg = id / (18 * 64);
        int tap = p >> 1, m = p & 1;
        int oc = ocg * 16 + (lane & 15);
        int ic0 = m * 32 + (lane >> 4) * 8;
#pragma unroll
        for (int j = 0; j < 8; ++j)
            o[j] = f2bf(Wf1[((size_t)oc * 64 + ic0 + j) * 9 + tap]);
        *(uint4*)(wt1 + (size_t)id * 8) = *(uint4*)o;
    } else {
        int id2 = id - 4608;                   // 2 ocg * 18 p * 64 lanes
        int lane = id2 & 63; int p = (id2 >> 6) % 18; int ocg = id2 / (18 * 64);
        int tap = p >> 1, m = p & 1;
        int oc = ocg * 16 + (lane & 15);
        int ic0 = m * 32 + (lane >> 4) * 8;
#pragma unroll
        for (int j = 0; j < 8; ++j)
            o[j] = (oc < 25) ? f2bf(Wf2[((size_t)oc * 64 + ic0 + j) * 9 + tap]) : (ushort_t)0;
        *(uint4*)(wt2 + (size_t)id2 * 8) = *(uint4*)o;
    }
}

// 1x1 conv as MFMA GEMM: qkv[b,o<128,px] = sum_c Wqkv[o][c] x[b,c,px].
__global__ __launch_bounds__(256) void k1_mfma(const float* __restrict__ x,
                                               const float* __restrict__ Wqkv,
                                               float* __restrict__ qkv) {
    int blk = blockIdx.x;              // 1024 = 8 b * 8 otile * 16 pxblk
    int tid = threadIdx.x, lane = tid & 63, wv = tid >> 6;
    int px0 = (blk & 15) * 256 + wv * 64;
    int otile = (blk >> 4) & 7, b = blk >> 7;
    int ln15 = lane & 15, g4 = (lane >> 4) * 4;

    const float* xb = x + (size_t)b * 64 * HW_;
    s4v wf[4];
#pragma unroll
    for (int k = 0; k < 4; ++k) {
        const float* wr = Wqkv + (size_t)(otile * 16 + ln15) * 64 + k * 16 + g4;
        float4 w4 = *(const float4*)wr;
        u2v u; u.x = bfpack_t(w4.x, w4.y); u.y = bfpack_t(w4.z, w4.w);
        wf[k] = __builtin_bit_cast(s4v, u);
    }
    const f4v zf = {0.f, 0.f, 0.f, 0.f};
    f4v acc[4] = {zf, zf, zf, zf};
#pragma unroll
    for (int k = 0; k < 4; ++k) {
#pragma unroll
        for (int p = 0; p < 4; ++p) {
            const float* xp = xb + (size_t)(k * 16 + g4) * HW_ + px0 + p * 16 + ln15;
            float v0 = xp[0];
            float v1 = xp[HW_];
            float v2 = xp[2 * HW_];
            float v3 = xp[3 * HW_];
            u2v u; u.x = bfpack_t(v0, v1); u.y = bfpack_t(v2, v3);
            s4v xf = __builtin_bit_cast(s4v, u);
            acc[p] = MFMA16(wf[k], xf, acc[p]);
        }
    }
    float* ob = qkv + ((size_t)b * 128 + otile * 16) * HW_ + px0;
#pragma unroll
    for (int p = 0; p < 4; ++p)
#pragma unroll
        for (int j = 0; j < 4; ++j)
            ob[(size_t)(g4 + j) * HW_ + p * 16 + ln15] = acc[p][j];
}

// depthwise 3x3 (zero pad). q (o<64) -> qbuf ; k (64<=o<128) -> k_out/v_out t=1 slots
__global__ __launch_bounds__(256) void k2_dw(const float* __restrict__ qkv,
                                             const float* __restrict__ Wdw,
                                             float* __restrict__ qbuf,
                                             float* __restrict__ k_out,
                                             float* __restrict__ v_out) {
    int t = blockIdx.x * 256 + threadIdx.x;   // 8*128*4096
    int hw = t & 4095; int bo = t >> 12; int o = bo & 127; int b = bo >> 7;
    int y = hw >> 6, xx0 = hw & 63;
    const float* in = qkv + (size_t)bo * HW_;
    const float* w = Wdw + o * 9;
    float acc = 0.f;
#pragma unroll
    for (int dy = 0; dy < 3; ++dy) {
        int yy = y + dy - 1;
        if (yy < 0 || yy > 63) continue;
#pragma unroll
        for (int dx = 0; dx < 3; ++dx) {
            int xx = xx0 + dx - 1;
            if (xx < 0 || xx > 63) continue;
            acc = fmaf(in[yy * 64 + xx], w[dy * 3 + dx], acc);
        }
    }
    if (o < 64) {
        qbuf[((size_t)b * 64 + o) * HW_ + hw] = acc;
    } else {
        int oc = o - 64;
        size_t off = (((size_t)b * 64 + oc) * 2 + 1) * HW_ + hw;
        k_out[off] = acc;   // k_ t=1
        v_out[off] = acc;   // v_ t=1  (reference uses k, not v!)
    }
}

// MFMA implicit-GEMM conv 3x3 64->64 + LeakyReLU, bf16 in/out fp32 accum.
__global__ __launch_bounds__(256) void k3_mfma1(const float* __restrict__ k_out,
                                                const float* __restrict__ vc,
                                                const ushort_t* __restrict__ wt1,
                                                ushort_t* __restrict__ fb16) {
    int stripe = blockIdx.x;  // 0..31
    int f = blockIdx.y;       // 0..23
    int tid = threadIdx.x;
    __shared__ ushort_t ilds[4 * 66 * 72];
    const float* src; size_t icstr;
    if (f < 16) { src = k_out + (((size_t)(f >> 1) * 128) + (f & 1)) * HW_; icstr = 2 * HW_; }
    else        { src = vc + ((size_t)(f - 16) * 64) * HW_;                 icstr = HW_; }
    int y0 = stripe * 2;

    int lane = tid & 63, wv = tid >> 6, g = lane >> 4, c16 = lane & 15;
    s8v a[18];
    const ushort_t* wb = wt1 + ((size_t)wv * 18) * 512 + lane * 8;
#pragma unroll
    for (int p = 0; p < 18; ++p) a[p] = *(const s8v*)(wb + p * 512);

    {
        int rc = tid >> 5, idx = tid & 31;
        int r = rc >> 1, side = rc & 1;
        ((unsigned int*)ilds)[(r * 66 + side * 65) * 36 + idx] = 0u;
    }
    {
        int r = tid >> 6, x = tid & 63;
        int y = y0 - 1 + r;
        bool valid = (y >= 0 && y < 64);
        const float* rowp = src + y * 64 + x;
        ushort_t* dst = ilds + ((r * 66) + x + 1) * 72;
#pragma unroll
        for (int ic4 = 0; ic4 < 16; ++ic4) {
            ushort_t o[4];
#pragma unroll
            for (int j = 0; j < 4; ++j) {
                float v = valid ? rowp[(size_t)(ic4 * 4 + j) * icstr] : 0.f;
                o[j] = f2bf(v);
            }
            *(uint2*)(dst + ic4 * 4) = *(uint2*)o;
        }
    }
    __syncthreads();

#pragma unroll
    for (int r_out = 0; r_out < 2; ++r_out)
#pragma unroll
        for (int xp = 0; xp < 2; ++xp) {
            int x0 = xp * 32, x1 = x0 + 16;
            f4v acc0 = {0.f, 0.f, 0.f, 0.f}, acc1 = {0.f, 0.f, 0.f, 0.f};
#pragma unroll
            for (int tap = 0; tap < 9; ++tap) {
                const int dy = tap / 3, dx = tap % 3;
                const ushort_t* bp0 = ilds + (((r_out + dy) * 66) + x0 + c16 + dx) * 72 + g * 8;
                const ushort_t* bp1 = ilds + (((r_out + dy) * 66) + x1 + c16 + dx) * 72 + g * 8;
                s8v b00 = *(const s8v*)bp0;          // ic g*8..+7
                s8v b01 = *(const s8v*)(bp0 + 32);   // ic 32+g*8..+7
                s8v b10 = *(const s8v*)bp1;
                s8v b11 = *(const s8v*)(bp1 + 32);
                acc0 = MFMA16(LO4(a[2 * tap]),     LO4(b00), acc0);
                acc1 = MFMA16(LO4(a[2 * tap]),     LO4(b10), acc1);
                acc0 = MFMA16(HI4(a[2 * tap]),     HI4(b00), acc0);
                acc1 = MFMA16(HI4(a[2 * tap]),     HI4(b10), acc1);
                acc0 = MFMA16(LO4(a[2 * tap + 1]), LO4(b01), acc0);
                acc1 = MFMA16(LO4(a[2 * tap + 1]), LO4(b11), acc1);
                acc0 = MFMA16(HI4(a[2 * tap + 1]), HI4(b01), acc0);
                acc1 = MFMA16(HI4(a[2 * tap + 1]), HI4(b11), acc1);
            }
            int py = (y0 + r_out) * 64;
#pragma unroll
            for (int j = 0; j < 4; ++j) {
                int oc = wv * 16 + g * 4 + j;
                float v0 = acc0[j]; v0 = (v0 >= 0.f) ? v0 : 0.2f * v0;
                float v1 = acc1[j]; v1 = (v1 >= 0.f) ? v1 : 0.2f * v1;
                fb16[((size_t)f * 64 + oc) * HW_ + py + x0 + c16] = f2bf(v0);
                fb16[((size_t)f * 64 + oc) * HW_ + py + x1 + c16] = f2bf(v1);
            }
        }
}

// MFMA implicit-GEMM conv 3x3 64->25 on bf16 fbuf -> kerb fp32.
__global__ __launch_bounds__(256) void k3b_mfma2(const ushort_t* __restrict__ fb16,
                                                 const ushort_t* __restrict__ wt2,
                                                 float* __restrict__ kerb) {
    int stripe = blockIdx.x;  // 0..31
    int f = blockIdx.y;       // 0..23
    int tid = threadIdx.x;
    __shared__ ushort_t ilds[4 * 66 * 72];
    int y0 = stripe * 2;

    int lane = tid & 63, wv = tid >> 6, g = lane >> 4, c16 = lane & 15;
    int ocg = wv & 1, xh = wv >> 1;
    s8v a[18];
    const ushort_t* wb = wt2 + ((size_t)ocg * 18) * 512 + lane * 8;
#pragma unroll
    for (int p = 0; p < 18; ++p) a[p] = *(const s8v*)(wb + p * 512);

    {
        int rc = tid >> 5, idx = tid & 31;
        int r = rc >> 1, side = rc & 1;
        ((unsigned int*)ilds)[(r * 66 + side * 65) * 36 + idx] = 0u;
    }
    {
        int r = tid >> 6, x = tid & 63;
        int y = y0 - 1 + r;
        bool valid = (y >= 0 && y < 64);
        const ushort_t* rowp = fb16 + (size_t)f * 64 * HW_ + y * 64 + x;
        ushort_t* dst = ilds + ((r * 66) + x + 1) * 72;
#pragma unroll
        for (int ic4 = 0; ic4 < 16; ++ic4) {
            ushort_t o[4];
#pragma unroll
            for (int j = 0; j < 4; ++j)
                o[j] = valid ? rowp[(size_t)(ic4 * 4 + j) * HW_] : (ushort_t)0;
            *(uint2*)(dst + ic4 * 4) = *(uint2*)o;
        }
    }
    __syncthreads();

#pragma unroll
    for (int r_out = 0; r_out < 2; ++r_out) {
        int x0 = xh * 32, x1 = x0 + 16;
        f4v acc0 = {0.f, 0.f, 0.f, 0.f}, acc1 = {0.f, 0.f, 0.f, 0.f};
#pragma unroll
        for (int tap = 0; tap < 9; ++tap) {
            const int dy = tap / 3, dx = tap % 3;
            const ushort_t* bp0 = ilds + (((r_out + dy) * 66) + x0 + c16 + dx) * 72 + g * 8;
            const ushort_t* bp1 = ilds + (((r_out + dy) * 66) + x1 + c16 + dx) * 72 + g * 8;
            s8v b00 = *(const s8v*)bp0;
            s8v b01 = *(const s8v*)(bp0 + 32);
            s8v b10 = *(const s8v*)bp1;
            s8v b11 = *(const s8v*)(bp1 + 32);
            acc0 = MFMA16(LO4(a[2 * tap]),     LO4(b00), acc0);
            acc1 = MFMA16(LO4(a[2 * tap]),     LO4(b10), acc1);
            acc0 = MFMA16(HI4(a[2 * tap]),     HI4(b00), acc0);
            acc1 = MFMA16(HI4(a[2 * tap]),     HI4(b10), acc1);
            acc0 = MFMA16(LO4(a[2 * tap + 1]), LO4(b01), acc0);
            acc1 = MFMA16(LO4(a[2 * tap + 1]), LO4(b11), acc1);
            acc0 = MFMA16(HI4(a[2 * tap + 1]), HI4(b01), acc0);
            acc1 = MFMA16(HI4(a[2 * tap + 1]), HI4(b11), acc1);
        }
        int py = (y0 + r_out) * 64;
#pragma unroll
        for (int j = 0; j < 4; ++j) {
            int oc = ocg * 16 + g * 4 + j;
            if (oc < 25) {
                kerb[((size_t)f * 25 + oc) * HW_ + py + x0 + c16] = acc0[j];
                kerb[((size_t)f * 25 + oc) * HW_ + py + x1 + c16] = acc1[j];
            }
        }
    }
}

// apply 50-tap dynamic filter; kern staged + mean fused in LDS.
// Register sliding-window over px (r12 structure). __launch_bounds__(256,4):
// r12's default bounds made the allocator target 8 waves/EU (VGPR=32) and
// squeeze the 12-wide windows out of registers (VALUBusy 41->18%). Min-waves=4
// caps VGPR at 128 so the working set (~40 floats) stays in registers.
__global__ __launch_bounds__(256, 4) void k4b_apply(const float* __restrict__ kerb,
                                                    const float* __restrict__ k_out,
                                                    const float* __restrict__ v_out,
                                                    float* __restrict__ kfil,
                                                    float* __restrict__ vfil) {
    int y = blockIdx.x, b = blockIdx.y;
    int p = blockIdx.z >> 1, chh = blockIdx.z & 1;
    int tid = threadIdx.x;
    __shared__ float klds[50][64];
    __shared__ float part[4][64];
    int f0 = (p == 0) ? 2 * b : 16 + b;
    int f1 = 2 * b + 1;
    // stage raw kernel taps
    for (int idx = tid; idx < 3200; idx += 256) {
        int px_ = idx & 63, j = idx >> 6;      // j in [0,50)
        int ti = (j >= 25); int kk = j - ti * 25;
        int fr = ti ? f1 : f0;
        klds[j][px_] = kerb[((size_t)fr * 25 + kk) * HW_ + y * 64 + px_];
    }
    __syncthreads();
    // fused mean over the 50 taps
    {
        int px_ = tid & 63, q_ = tid >> 6;
        int j0 = q_ * 13; int j1 = j0 + 13; if (j1 > 50) j1 = 50;
        float s = 0.f;
        for (int j = j0; j < j1; ++j) s += klds[j][px_];
        part[q_][px_] = s;
    }
    __syncthreads();
    if (tid < 64) {
        float m = (part[0][tid] + part[1][tid]) + (part[2][tid] + part[3][tid]);
        part[0][tid] = m * (1.f / 50.f);
    }
    __syncthreads();
    for (int idx = tid; idx < 3200; idx += 256) {
        int px_ = idx & 63, j = idx >> 6;
        klds[j][px_] += 0.02f - part[0][px_];
    }
    __syncthreads();

    int pg = tid & 15, cg = tid >> 4;
    int px4 = pg * 4;
    const float* xsrc = ((p == 0) ? k_out : v_out)
                      + ((size_t)b * 64 + chh * 32 + cg * 2) * 2 * HW_;
    float acc0[4] = {0.f, 0.f, 0.f, 0.f};
    float acc1[4] = {0.f, 0.f, 0.f, 0.f};
    bool ledge = (px4 == 0), redge = (px4 == 60);
    int loff = ledge ? 0 : px4 - 4;
    int roff = redge ? 60 : px4 + 4;

#pragma unroll
    for (int ti = 0; ti < 2; ++ti) {
#pragma unroll
        for (int r = 0; r < 5; ++r) {
            int cy = y + r - 2; cy = cy < 0 ? 0 : (cy > 63 ? 63 : cy);
            const float* sp0 = xsrc + (size_t)ti * HW_ + cy * 64;
            const float* sp1 = sp0 + 2 * HW_;
            float xw0[12], xw1[12];
            {
                float4 l4 = *(const float4*)(sp0 + loff);
                float4 m4 = *(const float4*)(sp0 + px4);
                float4 r4 = *(const float4*)(sp0 + roff);
                xw0[0] = l4.x; xw0[1] = l4.y;
                xw0[2] = ledge ? l4.x : l4.z;
                xw0[3] = ledge ? l4.x : l4.w;
                xw0[4] = m4.x; xw0[5] = m4.y; xw0[6] = m4.z; xw0[7] = m4.w;
                xw0[8] = redge ? r4.w : r4.x;
                xw0[9] = redge ? r4.w : r4.y;
                xw0[10] = r4.z; xw0[11] = r4.w;
            }
            {
                float4 l4 = *(const float4*)(sp1 + loff);
                float4 m4 = *(const float4*)(sp1 + px4);
                float4 r4 = *(const float4*)(sp1 + roff);
                xw1[0] = l4.x; xw1[1] = l4.y;
                xw1[2] = ledge ? l4.x : l4.z;
                xw1[3] = ledge ? l4.x : l4.w;
                xw1[4] = m4.x; xw1[5] = m4.y; xw1[6] = m4.z; xw1[7] = m4.w;
                xw1[8] = redge ? r4.w : r4.x;
                xw1[9] = redge ? r4.w : r4.y;
                xw1[10] = r4.z; xw1[11] = r4.w;
            }
#pragma unroll
            for (int dx = 0; dx < 5; ++dx) {
                float4 kv = *(const float4*)&klds[ti * 25 + r * 5 + dx][px4];
                float kva[4] = {kv.x, kv.y, kv.z, kv.w};
#pragma unroll
                for (int i = 0; i < 4; ++i) {
                    acc0[i] = fmaf(xw0[i + dx + 2], kva[i], acc0[i]);
                    acc1[i] = fmaf(xw1[i + dx + 2], kva[i], acc1[i]);
                }
            }
        }
    }
    float* ob = ((p == 0) ? kfil : vfil)
              + ((size_t)b * 64 + chh * 32 + cg * 2) * HW_ + y * 64 + px4;
    *(float4*)ob = *(float4*)acc0;
    *(float4*)(ob + HW_) = *(float4*)acc1;
}

// L2-normalize per (pixel, head) and convert to bf16 in MFMA-friendly layout:
// qbf/kbf[unit][row 0..1023][ch 0..15], unit = ((b*4+head)*4 + win)
__global__ __launch_bounds__(256) void k4c_cvt(const float* __restrict__ qbuf,
                                               const float* __restrict__ kfil,
                                               unsigned short* __restrict__ qbf,
                                               unsigned short* __restrict__ kbf) {
    int row = blockIdx.x * 256 + threadIdx.x;     // 0..1023
    int unit = blockIdx.y;                        // 128
    int which = blockIdx.z;                       // 0=q, 1=k
    int win = unit & 3, head = (unit >> 2) & 3, b = unit >> 4;
    int wy = win >> 1, wx = win & 1;
    int gpx = ((wy * 32 + (row >> 5)) << 6) + wx * 32 + (row & 31);
    const float* src = (which ? kfil : qbuf) + ((size_t)b * 64 + head * 16) * HW_ + gpx;
    float v[16]; float ss = 0.f;
#pragma unroll
    for (int i = 0; i < 16; ++i) { v[i] = src[(size_t)i * HW_]; ss = fmaf(v[i], v[i], ss); }
    float sc = 1.f / fmaxf(sqrtf(ss), 1e-12f);
    unsigned short o[16];
#pragma unroll
    for (int i = 0; i < 16; ++i) o[i] = f2bf(v[i] * sc);
    unsigned short* dst = (which ? kbf : qbf) + ((size_t)unit * 1024 + row) * 16;
    ((uint4*)dst)[0] = ((uint4*)o)[0];
    ((uint4*)dst)[1] = ((uint4*)o)[1];
}

// MFMA windowed attention (fixed-max softmax, exact since |q.k|<=~1).
// P->bf16 via perm TRUNCATION; l via ones-MFMA on the matrix pipe (numerator and
// denominator then sum the SAME truncated P -> bias cancels); exp2 via raw builtin.
__global__ __launch_bounds__(256) void k5_mfma(const unsigned short* __restrict__ qbf,
                                               const unsigned short* __restrict__ kbf,
                                               const float* __restrict__ vfil,
                                               const float* __restrict__ temp,
                                               float* __restrict__ attno) {
    int qb = blockIdx.x;          // 8
    int unit = blockIdx.y;        // 128
    int win = unit & 3, head = (unit >> 2) & 3, b = unit >> 4;
    int wy = win >> 1, wx = win & 1;
    int tid = threadIdx.x, lane = tid & 63, wv = tid >> 6;
    __shared__ unsigned short vt[16][1032];   // V^T bf16, row padded
    size_t cbase = ((size_t)b * 64 + head * 16) * HW_;

#pragma unroll
    for (int it = 0; it < 4; ++it) {
        int i = it * 256 + tid;                 // 1024 = 16 ch * 64 key-chunks
        int ch = i >> 6, k16 = (i & 63) << 4;
        int gpx = ((wy * 32 + (k16 >> 5)) << 6) + wx * 32 + (k16 & 31);
        const float* src = vfil + cbase + (size_t)ch * HW_ + gpx;
        unsigned int w[8];
#pragma unroll
        for (int j = 0; j < 8; ++j) w[j] = bfpack_t(src[2 * j], src[2 * j + 1]);
        uint4* d = (uint4*)&vt[ch][k16];
        d[0] = *(uint4*)&w[0];
        d[1] = *(uint4*)&w[4];
    }

    float tmp = temp[head];
    float a_s = tmp * 1.44269504f;
    float b_s = (fabsf(tmp) + 1e-6f) * 1.44269504f;

    int ln15 = lane & 15, g4 = (lane >> 4) * 4;
    const unsigned short* qu = qbf + (size_t)unit * 1024 * 16;
    const unsigned short* ku = kbf + (size_t)unit * 1024 * 16;
    int qt0 = qb * 8 + wv * 2;
    s4v qf0 = *(const s4v*)(qu + ((size_t)(qt0 * 16 + ln15)) * 16 + g4);
    s4v qf1 = *(const s4v*)(qu + ((size_t)((qt0 + 1) * 16 + ln15)) * 16 + g4);

    const short one_bf = (short)0x3F80;                       // bf16(1.0)
    const s4v ones = {one_bf, one_bf, one_bf, one_bf};
    const f4v zf = {0.f, 0.f, 0.f, 0.f};
    f4v o0 = zf, o1 = zf, lacc0 = zf, lacc1 = zf;

    __syncthreads();
    for (int tb = 0; tb < 64; ++tb) {
        s4v kf = *(const s4v*)(ku + ((size_t)(tb * 16 + ln15)) * 16 + g4);
        s4v vf = *(const s4v*)(&vt[ln15][tb * 16 + g4]);
        f4v s0 = MFMA16(kf, qf0, zf);
        f4v s1 = MFMA16(kf, qf1, zf);
        float p00 = __builtin_amdgcn_exp2f(fmaf(s0[0], a_s, -b_s));
        float p01 = __builtin_amdgcn_exp2f(fmaf(s0[1], a_s, -b_s));
        float p02 = __builtin_amdgcn_exp2f(fmaf(s0[2], a_s, -b_s));
        float p03 = __builtin_amdgcn_exp2f(fmaf(s0[3], a_s, -b_s));
        float p10 = __builtin_amdgcn_exp2f(fmaf(s1[0], a_s, -b_s));
        float p11 = __builtin_amdgcn_exp2f(fmaf(s1[1], a_s, -b_s));
        float p12 = __builtin_amdgcn_exp2f(fmaf(s1[2], a_s, -b_s));
        float p13 = __builtin_amdgcn_exp2f(fmaf(s1[3], a_s, -b_s));
        u2v u0; u0.x = bfpack_t(p00, p01); u0.y = bfpack_t(p02, p03);
        u2v u1; u1.x = bfpack_t(p10, p11); u1.y = bfpack_t(p12, p13);
        s4v pf0 = __builtin_bit_cast(s4v, u0);
        s4v pf1 = __builtin_bit_cast(s4v, u1);
        o0 = MFMA16(vf, pf0, o0);
        o1 = MFMA16(vf, pf1, o1);
        lacc0 = MFMA16(ones, pf0, lacc0);     // row-sums on the matrix pipe
        lacc1 = MFMA16(ones, pf1, lacc1);
    }

    float inv0 = 1.f / lacc0[0], inv1 = 1.f / lacc1[0];

    int q0 = qt0 * 16 + ln15;
    int q1 = q0 + 16;
    int gq0 = ((wy * 32 + (q0 >> 5)) << 6) + wx * 32 + (q0 & 31);
    int gq1 = ((wy * 32 + (q1 >> 5)) << 6) + wx * 32 + (q1 & 31);
#pragma unroll
    for (int j = 0; j < 4; ++j) {
        attno[cbase + (size_t)(g4 + j) * HW_ + gq0] = o0[j] * inv0;
        attno[cbase + (size_t)(g4 + j) * HW_ + gq1] = o1[j] * inv1;
    }
}

// 1x1 proj as MFMA GEMM: out[b,o,px] = sum_c Wp[o][c] attno[b,c,px].
__global__ __launch_bounds__(256) void k6_mfma(const float* __restrict__ attno,
                                               const float* __restrict__ Wp,
                                               float* __restrict__ out) {
    int blk = blockIdx.x;              // 512 = 8 b * 4 otile * 16 pxblk
    int tid = threadIdx.x, lane = tid & 63, wv = tid >> 6;
    int px0 = (blk & 15) * 256 + wv * 64;
    int otile = (blk >> 4) & 3, b = blk >> 6;
    int ln15 = lane & 15, g4 = (lane >> 4) * 4;

    const float* ab = attno + (size_t)b * 64 * HW_;
    s4v wf[4];
#pragma unroll
    for (int k = 0; k < 4; ++k) {
        const float* wr = Wp + (size_t)(otile * 16 + ln15) * 64 + k * 16 + g4;
        float4 w4 = *(const float4*)wr;
        u2v u; u.x = bfpack_t(w4.x, w4.y); u.y = bfpack_t(w4.z, w4.w);
        wf[k] = __builtin_bit_cast(s4v, u);
    }
    const f4v zf = {0.f, 0.f, 0.f, 0.f};
    f4v acc[4] = {zf, zf, zf, zf};
#pragma unroll
    for (int k = 0; k < 4; ++k) {
#pragma unroll
        for (int p = 0; p < 4; ++p) {
            const float* xp = ab + (size_t)(k * 16 + g4) * HW_ + px0 + p * 16 + ln15;
            float v0 = xp[0];
            float v1 = xp[HW_];
            float v2 = xp[2 * HW_];
            float v3 = xp[3 * HW_];
            u2v u; u.x = bfpack_t(v0, v1); u.y = bfpack_t(v2, v3);
            s4v xf = __builtin_bit_cast(s4v, u);
            acc[p] = MFMA16(wf[k], xf, acc[p]);
        }
    }
    float* ob = out + ((size_t)b * 64 + otile * 16) * HW_ + px0;
#pragma unroll
    for (int p = 0; p < 4; ++p)
#pragma unroll
        for (int j = 0; j < 4; ++j)
            ob[(size_t)(g4 + j) * HW_ + p * 16 + ln15] = acc[p][j];
}

extern "C" void kernel_launch(void* const* d_in, const int* in_sizes, int n_in,
                              void* d_out, int out_size, void* d_ws, size_t ws_size,
                              hipStream_t stream) {
    const float* x    = (const float*)d_in[0];
    const float* kc   = (const float*)d_in[1];
    const float* vc   = (const float*)d_in[2];
    const float* Wqkv = (const float*)d_in[3];
    const float* Wdw  = (const float*)d_in[4];
    const float* Wf1  = (const float*)d_in[5];
    const float* Wf2  = (const float*)d_in[6];
    const float* Wpr  = (const float*)d_in[7];
    const float* temp = (const float*)d_in[8];

    float* out   = (float*)d_out;
    float* k_out = out + OUT_N;            // (8,64,2,64,64)
    float* v_out = out + OUT_N + KV_N;

    float* ws   = (float*)d_ws;
    float* qkv  = ws;                      // [0 .. 4.19M floats) — dead after k2
    unsigned short* fb16 = (unsigned short*)ws;            // 6.29M shorts (reuses qkv region after k2)
    unsigned short* qbf = (unsigned short*)ws;             // 2M shorts (after fb16 dead)
    unsigned short* kbf = (unsigned short*)(ws + 1048576); // 2M shorts
    float* qbuf = ws + 6291456;            // 2,097,152
    float* kerb = ws + 8388608;            // 2,457,600
    float* kfil = ws + 10846208;           // 2,097,152
    float* vfil = ws + 12943360;           // 2,097,152
    unsigned short* wt1 = (unsigned short*)(ws + 15106048); // 36864 shorts
    unsigned short* wt2 = wt1 + 36864;                      // 18432 shorts
    float* attno= kerb;                    // alias: kerb free after k4b

    wprep   <<<27,    256, 0, stream>>>(Wf1, Wf2, wt1, wt2);
    k0_copy <<<4096,  256, 0, stream>>>((const float4*)kc, (const float4*)vc, k_out, v_out);
    k1_mfma <<<1024,  256, 0, stream>>>(x, Wqkv, qkv);
    k2_dw   <<<16384, 256, 0, stream>>>(qkv, Wdw, qbuf, k_out, v_out);
    k3_mfma1<<<dim3(32, 24), 256, 0, stream>>>(k_out, vc, wt1, fb16);
    k3b_mfma2<<<dim3(32, 24), 256, 0, stream>>>(fb16, wt2, kerb);
    k4b_apply<<<dim3(64, 8, 4), 256, 0, stream>>>(kerb, k_out, v_out, kfil, vfil);
    k4c_cvt <<<dim3(4, 128, 2), 256, 0, stream>>>(qbuf, kfil, qbf, kbf);
    k5_mfma <<<dim3(8, 128), 256, 0, stream>>>(qbf, kbf, vfil, temp, attno);
    k6_mfma <<<512,   256, 0, stream>>>(attno, Wpr, out);
}

// Round 14
// 173.080 us; speedup vs baseline: 1.0678x; 1.0515x over previous
//
#include <hip/hip_runtime.h>
#include <math.h>

// ---- problem constants ----
// b=8, c=64, h=w=64, HEADS=4 ch=16, PATCH=32 -> windows [0,32]x[0,32] disjoint
// t=2 (cached frame + new frame), KSIZE=5 (25 taps), K=50
#define B_ 8
#define C_ 64
#define HW_ 4096

// d_out regions (floats)
#define OUT_N   2097152   // (8,64,64,64)
#define KV_N    4194304   // (8,64,2,64,64)

typedef short s4v __attribute__((ext_vector_type(4)));
typedef short s8v __attribute__((ext_vector_type(8)));
typedef float f4v __attribute__((ext_vector_type(4)));
typedef unsigned int u2v __attribute__((ext_vector_type(2)));
typedef unsigned short ushort_t;

__device__ inline unsigned short f2bf(float f) {
    unsigned int u = __builtin_bit_cast(unsigned int, f);
    u += 0x7FFFu + ((u >> 16) & 1u);      // round-to-nearest-even bf16
    return (unsigned short)(u >> 16);
}

// packed fp32->bf16x2 by byte-perm TRUNCATION (no rounding adds): a->lo, b->hi
__device__ inline unsigned int bfpack_t(float a, float b) {
    unsigned int ua = __builtin_bit_cast(unsigned int, a);
    unsigned int ub = __builtin_bit_cast(unsigned int, b);
    return __builtin_amdgcn_perm(ub, ua, 0x07060302u);
}

#define MFMA16(a, b, c) __builtin_amdgcn_mfma_f32_16x16x16bf16_1k(a, b, c, 0, 0, 0)
#define LO4(v) __builtin_shufflevector(v, v, 0, 1, 2, 3)
#define HI4(v) __builtin_shufflevector(v, v, 4, 5, 6, 7)

// float4 cache->output copy: 4096 blocks cover 2 * (B*C*HW/4) float4s
__global__ __launch_bounds__(256) void k0_copy(const float4* __restrict__ kc,
                                               const float4* __restrict__ vc,
                                               float* __restrict__ k_out,
                                               float* __restrict__ v_out) {
    int i = blockIdx.x * 256 + threadIdx.x;
    const int n4 = (B_ * C_ * HW_) / 4;
    int which = (i >= n4);
    int j = which ? i - n4 : i;
    const float4* src = which ? vc : kc;
    float4 v = src[j];
    int bc = j >> 10, hw4 = j & 1023;        // 1024 float4 per (b,c)
    float* dst = (which ? v_out : k_out) + ((size_t)bc * 2) * HW_ + hw4 * 4;
    *(float4*)dst = v;                        // t = 0 slot
}

// weight prep: swizzle Wf1/Wf2 into MFMA A-fragment layout (bf16).
__global__ __launch_bounds__(256) void wprep(const float* __restrict__ Wf1,
                                             const float* __restrict__ Wf2,
                                             ushort_t* __restrict__ wt1,
                                             ushort_t* __restrict__ wt2) {
    int id = blockIdx.x * 256 + threadIdx.x;   // 0..6911
    if (id >= 6912) return;
    ushort_t o[8];
    if (id < 4608) {                           // 4 ocg * 18 p * 64 lanes
        int lane = id & 63; int p = (id >> 6) % 18; int ocg = id / (18 * 64);
        int tap = p >> 1, m = p & 1;
        int oc = ocg * 16 + (lane & 15);
        int ic0 = m * 32 + (lane >> 4) * 8;
#pragma unroll
        for (int j = 0; j < 8; ++j)
            o[j] = f2bf(Wf1[((size_t)oc * 64 + ic0 + j) * 9 + tap]);
        *(uint4*)(wt1 + (size_t)id * 8) = *(uint4*)o;
    } else {
        int id2 = id - 4608;                   // 2 ocg * 18 p * 64 lanes
        int lane = id2 & 63; int p = (id2 >> 6) % 18; int ocg = id2 / (18 * 64);
        int tap = p >> 1, m = p & 1;
        int oc = ocg * 16 + (lane & 15);
        int ic0 = m * 32 + (lane >> 4) * 8;
#pragma unroll
        for (int j = 0; j < 8; ++j)
            o[j] = (oc < 25) ? f2bf(Wf2[((size_t)oc * 64 + ic0 + j) * 9 + tap]) : (ushort_t)0;
        *(uint4*)(wt2 + (size_t)id2 * 8) = *(uint4*)o;
    }
}

// 1x1 conv as MFMA GEMM: qkv[b,o<128,px] = sum_c Wqkv[o][c] x[b,c,px].
__global__ __launch_bounds__(256) void k1_mfma(const float* __restrict__ x,
                                               const float* __restrict__ Wqkv,
                                               float* __restrict__ qkv) {
    int blk = blockIdx.x;              // 1024 = 8 b * 8 otile * 16 pxblk
    int tid = threadIdx.x, lane = tid & 63, wv = tid >> 6;
    int px0 = (blk & 15) * 256 + wv * 64;
    int otile = (blk >> 4) & 7, b = blk >> 7;
    int ln15 = lane & 15, g4 = (lane >> 4) * 4;

    const float* xb = x + (size_t)b * 64 * HW_;
    s4v wf[4];
#pragma unroll
    for (int k = 0; k < 4; ++k) {
        const float* wr = Wqkv + (size_t)(otile * 16 + ln15) * 64 + k * 16 + g4;
        float4 w4 = *(const float4*)wr;
        u2v u; u.x = bfpack_t(w4.x, w4.y); u.y = bfpack_t(w4.z, w4.w);
        wf[k] = __builtin_bit_cast(s4v, u);
    }
    const f4v zf = {0.f, 0.f, 0.f, 0.f};
    f4v acc[4] = {zf, zf, zf, zf};
#pragma unroll
    for (int k = 0; k < 4; ++k) {
#pragma unroll
        for (int p = 0; p < 4; ++p) {
            const float* xp = xb + (size_t)(k * 16 + g4) * HW_ + px0 + p * 16 + ln15;
            float v0 = xp[0];
            float v1 = xp[HW_];
            float v2 = xp[2 * HW_];
            float v3 = xp[3 * HW_];
            u2v u; u.x = bfpack_t(v0, v1); u.y = bfpack_t(v2, v3);
            s4v xf = __builtin_bit_cast(s4v, u);
            acc[p] = MFMA16(wf[k], xf, acc[p]);
        }
    }
    float* ob = qkv + ((size_t)b * 128 + otile * 16) * HW_ + px0;
#pragma unroll
    for (int p = 0; p < 4; ++p)
#pragma unroll
        for (int j = 0; j < 4; ++j)
            ob[(size_t)(g4 + j) * HW_ + p * 16 + ln15] = acc[p][j];
}

// depthwise 3x3 (zero pad). q (o<64) -> qbuf ; k (64<=o<128) -> k_out/v_out t=1 slots
__global__ __launch_bounds__(256) void k2_dw(const float* __restrict__ qkv,
                                             const float* __restrict__ Wdw,
                                             float* __restrict__ qbuf,
                                             float* __restrict__ k_out,
                                             float* __restrict__ v_out) {
    int t = blockIdx.x * 256 + threadIdx.x;   // 8*128*4096
    int hw = t & 4095; int bo = t >> 12; int o = bo & 127; int b = bo >> 7;
    int y = hw >> 6, xx0 = hw & 63;
    const float* in = qkv + (size_t)bo * HW_;
    const float* w = Wdw + o * 9;
    float acc = 0.f;
#pragma unroll
    for (int dy = 0; dy < 3; ++dy) {
        int yy = y + dy - 1;
        if (yy < 0 || yy > 63) continue;
#pragma unroll
        for (int dx = 0; dx < 3; ++dx) {
            int xx = xx0 + dx - 1;
            if (xx < 0 || xx > 63) continue;
            acc = fmaf(in[yy * 64 + xx], w[dy * 3 + dx], acc);
        }
    }
    if (o < 64) {
        qbuf[((size_t)b * 64 + o) * HW_ + hw] = acc;
    } else {
        int oc = o - 64;
        size_t off = (((size_t)b * 64 + oc) * 2 + 1) * HW_ + hw;
        k_out[off] = acc;   // k_ t=1
        v_out[off] = acc;   // v_ t=1  (reference uses k, not v!)
    }
}

// MFMA implicit-GEMM conv 3x3 64->64 + LeakyReLU, bf16 in/out fp32 accum.
__global__ __launch_bounds__(256) void k3_mfma1(const float* __restrict__ k_out,
                                                const float* __restrict__ vc,
                                                const ushort_t* __restrict__ wt1,
                                                ushort_t* __restrict__ fb16) {
    int stripe = blockIdx.x;  // 0..31
    int f = blockIdx.y;       // 0..23
    int tid = threadIdx.x;
    __shared__ ushort_t ilds[4 * 66 * 72];
    const float* src; size_t icstr;
    if (f < 16) { src = k_out + (((size_t)(f >> 1) * 128) + (f & 1)) * HW_; icstr = 2 * HW_; }
    else        { src = vc + ((size_t)(f - 16) * 64) * HW_;                 icstr = HW_; }
    int y0 = stripe * 2;

    int lane = tid & 63, wv = tid >> 6, g = lane >> 4, c16 = lane & 15;
    s8v a[18];
    const ushort_t* wb = wt1 + ((size_t)wv * 18) * 512 + lane * 8;
#pragma unroll
    for (int p = 0; p < 18; ++p) a[p] = *(const s8v*)(wb + p * 512);

    {
        int rc = tid >> 5, idx = tid & 31;
        int r = rc >> 1, side = rc & 1;
        ((unsigned int*)ilds)[(r * 66 + side * 65) * 36 + idx] = 0u;
    }
    {
        int r = tid >> 6, x = tid & 63;
        int y = y0 - 1 + r;
        bool valid = (y >= 0 && y < 64);
        const float* rowp = src + y * 64 + x;
        ushort_t* dst = ilds + ((r * 66) + x + 1) * 72;
#pragma unroll
        for (int ic4 = 0; ic4 < 16; ++ic4) {
            ushort_t o[4];
#pragma unroll
            for (int j = 0; j < 4; ++j) {
                float v = valid ? rowp[(size_t)(ic4 * 4 + j) * icstr] : 0.f;
                o[j] = f2bf(v);
            }
            *(uint2*)(dst + ic4 * 4) = *(uint2*)o;
        }
    }
    __syncthreads();

#pragma unroll
    for (int r_out = 0; r_out < 2; ++r_out)
#pragma unroll
        for (int xp = 0; xp < 2; ++xp) {
            int x0 = xp * 32, x1 = x0 + 16;
            f4v acc0 = {0.f, 0.f, 0.f, 0.f}, acc1 = {0.f, 0.f, 0.f, 0.f};
#pragma unroll
            for (int tap = 0; tap < 9; ++tap) {
                const int dy = tap / 3, dx = tap % 3;
                const ushort_t* bp0 = ilds + (((r_out + dy) * 66) + x0 + c16 + dx) * 72 + g * 8;
                const ushort_t* bp1 = ilds + (((r_out + dy) * 66) + x1 + c16 + dx) * 72 + g * 8;
                s8v b00 = *(const s8v*)bp0;          // ic g*8..+7
                s8v b01 = *(const s8v*)(bp0 + 32);   // ic 32+g*8..+7
                s8v b10 = *(const s8v*)bp1;
                s8v b11 = *(const s8v*)(bp1 + 32);
                acc0 = MFMA16(LO4(a[2 * tap]),     LO4(b00), acc0);
                acc1 = MFMA16(LO4(a[2 * tap]),     LO4(b10), acc1);
                acc0 = MFMA16(HI4(a[2 * tap]),     HI4(b00), acc0);
                acc1 = MFMA16(HI4(a[2 * tap]),     HI4(b10), acc1);
                acc0 = MFMA16(LO4(a[2 * tap + 1]), LO4(b01), acc0);
                acc1 = MFMA16(LO4(a[2 * tap + 1]), LO4(b11), acc1);
                acc0 = MFMA16(HI4(a[2 * tap + 1]), HI4(b01), acc0);
                acc1 = MFMA16(HI4(a[2 * tap + 1]), HI4(b11), acc1);
            }
            int py = (y0 + r_out) * 64;
#pragma unroll
            for (int j = 0; j < 4; ++j) {
                int oc = wv * 16 + g * 4 + j;
                float v0 = acc0[j]; v0 = (v0 >= 0.f) ? v0 : 0.2f * v0;
                float v1 = acc1[j]; v1 = (v1 >= 0.f) ? v1 : 0.2f * v1;
                fb16[((size_t)f * 64 + oc) * HW_ + py + x0 + c16] = f2bf(v0);
                fb16[((size_t)f * 64 + oc) * HW_ + py + x1 + c16] = f2bf(v1);
            }
        }
}

// MFMA implicit-GEMM conv 3x3 64->25 on bf16 fbuf -> kerb fp32.
__global__ __launch_bounds__(256) void k3b_mfma2(const ushort_t* __restrict__ fb16,
                                                 const ushort_t* __restrict__ wt2,
                                                 float* __restrict__ kerb) {
    int stripe = blockIdx.x;  // 0..31
    int f = blockIdx.y;       // 0..23
    int tid = threadIdx.x;
    __shared__ ushort_t ilds[4 * 66 * 72];
    int y0 = stripe * 2;

    int lane = tid & 63, wv = tid >> 6, g = lane >> 4, c16 = lane & 15;
    int ocg = wv & 1, xh = wv >> 1;
    s8v a[18];
    const ushort_t* wb = wt2 + ((size_t)ocg * 18) * 512 + lane * 8;
#pragma unroll
    for (int p = 0; p < 18; ++p) a[p] = *(const s8v*)(wb + p * 512);

    {
        int rc = tid >> 5, idx = tid & 31;
        int r = rc >> 1, side = rc & 1;
        ((unsigned int*)ilds)[(r * 66 + side * 65) * 36 + idx] = 0u;
    }
    {
        int r = tid >> 6, x = tid & 63;
        int y = y0 - 1 + r;
        bool valid = (y >= 0 && y < 64);
        const ushort_t* rowp = fb16 + (size_t)f * 64 * HW_ + y * 64 + x;
        ushort_t* dst = ilds + ((r * 66) + x + 1) * 72;
#pragma unroll
        for (int ic4 = 0; ic4 < 16; ++ic4) {
            ushort_t o[4];
#pragma unroll
            for (int j = 0; j < 4; ++j)
                o[j] = valid ? rowp[(size_t)(ic4 * 4 + j) * HW_] : (ushort_t)0;
            *(uint2*)(dst + ic4 * 4) = *(uint2*)o;
        }
    }
    __syncthreads();

#pragma unroll
    for (int r_out = 0; r_out < 2; ++r_out) {
        int x0 = xh * 32, x1 = x0 + 16;
        f4v acc0 = {0.f, 0.f, 0.f, 0.f}, acc1 = {0.f, 0.f, 0.f, 0.f};
#pragma unroll
        for (int tap = 0; tap < 9; ++tap) {
            const int dy = tap / 3, dx = tap % 3;
            const ushort_t* bp0 = ilds + (((r_out + dy) * 66) + x0 + c16 + dx) * 72 + g * 8;
            const ushort_t* bp1 = ilds + (((r_out + dy) * 66) + x1 + c16 + dx) * 72 + g * 8;
            s8v b00 = *(const s8v*)bp0;
            s8v b01 = *(const s8v*)(bp0 + 32);
            s8v b10 = *(const s8v*)bp1;
            s8v b11 = *(const s8v*)(bp1 + 32);
            acc0 = MFMA16(LO4(a[2 * tap]),     LO4(b00), acc0);
            acc1 = MFMA16(LO4(a[2 * tap]),     LO4(b10), acc1);
            acc0 = MFMA16(HI4(a[2 * tap]),     HI4(b00), acc0);
            acc1 = MFMA16(HI4(a[2 * tap]),     HI4(b10), acc1);
            acc0 = MFMA16(LO4(a[2 * tap + 1]), LO4(b01), acc0);
            acc1 = MFMA16(LO4(a[2 * tap + 1]), LO4(b11), acc1);
            acc0 = MFMA16(HI4(a[2 * tap + 1]), HI4(b01), acc0);
            acc1 = MFMA16(HI4(a[2 * tap + 1]), HI4(b11), acc1);
        }
        int py = (y0 + r_out) * 64;
#pragma unroll
        for (int j = 0; j < 4; ++j) {
            int oc = ocg * 16 + g * 4 + j;
            if (oc < 25) {
                kerb[((size_t)f * 25 + oc) * HW_ + py + x0 + c16] = acc0[j];
                kerb[((size_t)f * 25 + oc) * HW_ + py + x1 + c16] = acc1[j];
            }
        }
    }
}

// apply 50-tap dynamic filter with edge-clamped input; kern staged + mean fused
// in LDS. PROVEN round-10 structure (L1-hot scalar x reads; VGPR=48, 44.0 us).
// grid (64 y, 8 b, 4 z=p*2+chh); thread (px, cq) owns 8 ch = chh*32 + cq + 4*i.
__global__ __launch_bounds__(256) void k4b_apply(const float* __restrict__ kerb,
                                                 const float* __restrict__ k_out,
                                                 const float* __restrict__ v_out,
                                                 float* __restrict__ kfil,
                                                 float* __restrict__ vfil) {
    int y = blockIdx.x, b = blockIdx.y;
    int p = blockIdx.z >> 1, chh = blockIdx.z & 1;
    int tid = threadIdx.x;
    __shared__ float klds[50][64];
    __shared__ float part[4][64];
    int f0 = (p == 0) ? 2 * b : 16 + b;
    int f1 = 2 * b + 1;
    // stage raw kernel taps
    for (int idx = tid; idx < 3200; idx += 256) {
        int px_ = idx & 63, j = idx >> 6;      // j in [0,50)
        int ti = (j >= 25); int kk = j - ti * 25;
        int fr = ti ? f1 : f0;
        klds[j][px_] = kerb[((size_t)fr * 25 + kk) * HW_ + y * 64 + px_];
    }
    __syncthreads();
    // fused mean over the 50 taps
    {
        int px_ = tid & 63, q_ = tid >> 6;
        int j0 = q_ * 13; int j1 = j0 + 13; if (j1 > 50) j1 = 50;
        float s = 0.f;
        for (int j = j0; j < j1; ++j) s += klds[j][px_];
        part[q_][px_] = s;
    }
    __syncthreads();
    if (tid < 64) {
        float m = (part[0][tid] + part[1][tid]) + (part[2][tid] + part[3][tid]);
        part[0][tid] = m * (1.f / 50.f);
    }
    __syncthreads();
    for (int idx = tid; idx < 3200; idx += 256) {
        int px_ = idx & 63, j = idx >> 6;
        klds[j][px_] += 0.02f - part[0][px_];
    }
    __syncthreads();

    int px = tid & 63, cq = tid >> 6;          // 4 c-phases, 8 c each (this half)
    const float* xsrc = ((p == 0) ? k_out : v_out)
                      + (size_t)b * 64 * 2 * HW_ + (size_t)chh * 32 * 2 * HW_;
    float acc[8];
#pragma unroll
    for (int i = 0; i < 8; ++i) acc[i] = 0.f;

#pragma unroll
    for (int ti = 0; ti < 2; ++ti) {
        for (int kk = 0; kk < 25; ++kk) {
            int cy = y + kk / 5 - 2;  cy = cy < 0 ? 0 : (cy > 63 ? 63 : cy);
            int cx = px + kk % 5 - 2; cx = cx < 0 ? 0 : (cx > 63 ? 63 : cx);
            float kv = klds[ti * 25 + kk][px];
            const float* xb = xsrc + (size_t)ti * HW_ + cy * 64 + cx;
#pragma unroll
            for (int i = 0; i < 8; ++i)
                acc[i] = fmaf(xb[(size_t)(cq + 4 * i) * 2 * HW_], kv, acc[i]);
        }
    }
    float* ob = ((p == 0) ? kfil : vfil)
              + ((size_t)b * 64 + chh * 32) * HW_ + y * 64 + px;
#pragma unroll
    for (int i = 0; i < 8; ++i) ob[(size_t)(cq + 4 * i) * HW_] = acc[i];
}

// L2-normalize per (pixel, head) and convert to bf16 in MFMA-friendly layout:
// qbf/kbf[unit][row 0..1023][ch 0..15], unit = ((b*4+head)*4 + win)
__global__ __launch_bounds__(256) void k4c_cvt(const float* __restrict__ qbuf,
                                               const float* __restrict__ kfil,
                                               unsigned short* __restrict__ qbf,
                                               unsigned short* __restrict__ kbf) {
    int row = blockIdx.x * 256 + threadIdx.x;     // 0..1023
    int unit = blockIdx.y;                        // 128
    int which = blockIdx.z;                       // 0=q, 1=k
    int win = unit & 3, head = (unit >> 2) & 3, b = unit >> 4;
    int wy = win >> 1, wx = win & 1;
    int gpx = ((wy * 32 + (row >> 5)) << 6) + wx * 32 + (row & 31);
    const float* src = (which ? kfil : qbuf) + ((size_t)b * 64 + head * 16) * HW_ + gpx;
    float v[16]; float ss = 0.f;
#pragma unroll
    for (int i = 0; i < 16; ++i) { v[i] = src[(size_t)i * HW_]; ss = fmaf(v[i], v[i], ss); }
    float sc = 1.f / fmaxf(sqrtf(ss), 1e-12f);
    unsigned short o[16];
#pragma unroll
    for (int i = 0; i < 16; ++i) o[i] = f2bf(v[i] * sc);
    unsigned short* dst = (which ? kbf : qbf) + ((size_t)unit * 1024 + row) * 16;
    ((uint4*)dst)[0] = ((uint4*)o)[0];
    ((uint4*)dst)[1] = ((uint4*)o)[1];
}

// MFMA windowed attention (fixed-max softmax, exact since |q.k|<=~1).
// P->bf16 via perm TRUNCATION; l via ones-MFMA on the matrix pipe; exp2 builtin.
// #pragma unroll 4 on the key loop: batches 4 independent kf global loads +
// vf ds_reads in flight (the serial load->MFMA->exp->MFMA chain with only
// 4 waves/SIMD leaves ~200cyc L2 latency exposed per iter otherwise).
__global__ __launch_bounds__(256) void k5_mfma(const unsigned short* __restrict__ qbf,
                                               const unsigned short* __restrict__ kbf,
                                               const float* __restrict__ vfil,
                                               const float* __restrict__ temp,
                                               float* __restrict__ attno) {
    int qb = blockIdx.x;          // 8
    int unit = blockIdx.y;        // 128
    int win = unit & 3, head = (unit >> 2) & 3, b = unit >> 4;
    int wy = win >> 1, wx = win & 1;
    int tid = threadIdx.x, lane = tid & 63, wv = tid >> 6;
    __shared__ unsigned short vt[16][1032];   // V^T bf16, row padded
    size_t cbase = ((size_t)b * 64 + head * 16) * HW_;

#pragma unroll
    for (int it = 0; it < 4; ++it) {
        int i = it * 256 + tid;                 // 1024 = 16 ch * 64 key-chunks
        int ch = i >> 6, k16 = (i & 63) << 4;
        int gpx = ((wy * 32 + (k16 >> 5)) << 6) + wx * 32 + (k16 & 31);
        const float* src = vfil + cbase + (size_t)ch * HW_ + gpx;
        unsigned int w[8];
#pragma unroll
        for (int j = 0; j < 8; ++j) w[j] = bfpack_t(src[2 * j], src[2 * j + 1]);
        uint4* d = (uint4*)&vt[ch][k16];
        d[0] = *(uint4*)&w[0];
        d[1] = *(uint4*)&w[4];
    }

    float tmp = temp[head];
    float a_s = tmp * 1.44269504f;
    float b_s = (fabsf(tmp) + 1e-6f) * 1.44269504f;

    int ln15 = lane & 15, g4 = (lane >> 4) * 4;
    const unsigned short* qu = qbf + (size_t)unit * 1024 * 16;
    const unsigned short* ku = kbf + (size_t)unit * 1024 * 16;
    int qt0 = qb * 8 + wv * 2;
    s4v qf0 = *(const s4v*)(qu + ((size_t)(qt0 * 16 + ln15)) * 16 + g4);
    s4v qf1 = *(const s4v*)(qu + ((size_t)((qt0 + 1) * 16 + ln15)) * 16 + g4);

    const short one_bf = (short)0x3F80;                       // bf16(1.0)
    const s4v ones = {one_bf, one_bf, one_bf, one_bf};
    const f4v zf = {0.f, 0.f, 0.f, 0.f};
    f4v o0 = zf, o1 = zf, lacc0 = zf, lacc1 = zf;

    __syncthreads();
#pragma unroll 4
    for (int tb = 0; tb < 64; ++tb) {
        s4v kf = *(const s4v*)(ku + ((size_t)(tb * 16 + ln15)) * 16 + g4);
        s4v vf = *(const s4v*)(&vt[ln15][tb * 16 + g4]);
        f4v s0 = MFMA16(kf, qf0, zf);
        f4v s1 = MFMA16(kf, qf1, zf);
        float p00 = __builtin_amdgcn_exp2f(fmaf(s0[0], a_s, -b_s));
        float p01 = __builtin_amdgcn_exp2f(fmaf(s0[1], a_s, -b_s));
        float p02 = __builtin_amdgcn_exp2f(fmaf(s0[2], a_s, -b_s));
        float p03 = __builtin_amdgcn_exp2f(fmaf(s0[3], a_s, -b_s));
        float p10 = __builtin_amdgcn_exp2f(fmaf(s1[0], a_s, -b_s));
        float p11 = __builtin_amdgcn_exp2f(fmaf(s1[1], a_s, -b_s));
        float p12 = __builtin_amdgcn_exp2f(fmaf(s1[2], a_s, -b_s));
        float p13 = __builtin_amdgcn_exp2f(fmaf(s1[3], a_s, -b_s));
        u2v u0; u0.x = bfpack_t(p00, p01); u0.y = bfpack_t(p02, p03);
        u2v u1; u1.x = bfpack_t(p10, p11); u1.y = bfpack_t(p12, p13);
        s4v pf0 = __builtin_bit_cast(s4v, u0);
        s4v pf1 = __builtin_bit_cast(s4v, u1);
        o0 = MFMA16(vf, pf0, o0);
        o1 = MFMA16(vf, pf1, o1);
        lacc0 = MFMA16(ones, pf0, lacc0);     // row-sums on the matrix pipe
        lacc1 = MFMA16(ones, pf1, lacc1);
    }

    float inv0 = 1.f / lacc0[0], inv1 = 1.f / lacc1[0];

    int q0 = qt0 * 16 + ln15;
    int q1 = q0 + 16;
    int gq0 = ((wy * 32 + (q0 >> 5)) << 6) + wx * 32 + (q0 & 31);
    int gq1 = ((wy * 32 + (q1 >> 5)) << 6) + wx * 32 + (q1 & 31);
#pragma unroll
    for (int j = 0; j < 4; ++j) {
        attno[cbase + (size_t)(g4 + j) * HW_ + gq0] = o0[j] * inv0;
        attno[cbase + (size_t)(g4 + j) * HW_ + gq1] = o1[j] * inv1;
    }
}

// 1x1 proj as MFMA GEMM: out[b,o,px] = sum_c Wp[o][c] attno[b,c,px].
__global__ __launch_bounds__(256) void k6_mfma(const float* __restrict__ attno,
                                               const float* __restrict__ Wp,
                                               float* __restrict__ out) {
    int blk = blockIdx.x;              // 512 = 8 b * 4 otile * 16 pxblk
    int tid = threadIdx.x, lane = tid & 63, wv = tid >> 6;
    int px0 = (blk & 15) * 256 + wv * 64;
    int otile = (blk >> 4) & 3, b = blk >> 6;
    int ln15 = lane & 15, g4 = (lane >> 4) * 4;

    const float* ab = attno + (size_t)b * 64 * HW_;
    s4v wf[4];
#pragma unroll
    for (int k = 0; k < 4; ++k) {
        const float* wr = Wp + (size_t)(otile * 16 + ln15) * 64 + k * 16 + g4;
        float4 w4 = *(const float4*)wr;
        u2v u; u.x = bfpack_t(w4.x, w4.y); u.y = bfpack_t(w4.z, w4.w);
        wf[k] = __builtin_bit_cast(s4v, u);
    }
    const f4v zf = {0.f, 0.f, 0.f, 0.f};
    f4v acc[4] = {zf, zf, zf, zf};
#pragma unroll
    for (int k = 0; k < 4; ++k) {
#pragma unroll
        for (int p = 0; p < 4; ++p) {
            const float* xp = ab + (size_t)(k * 16 + g4) * HW_ + px0 + p * 16 + ln15;
            float v0 = xp[0];
            float v1 = xp[HW_];
            float v2 = xp[2 * HW_];
            float v3 = xp[3 * HW_];
            u2v u; u.x = bfpack_t(v0, v1); u.y = bfpack_t(v2, v3);
            s4v xf = __builtin_bit_cast(s4v, u);
            acc[p] = MFMA16(wf[k], xf, acc[p]);
        }
    }
    float* ob = out + ((size_t)b * 64 + otile * 16) * HW_ + px0;
#pragma unroll
    for (int p = 0; p < 4; ++p)
#pragma unroll
        for (int j = 0; j < 4; ++j)
            ob[(size_t)(g4 + j) * HW_ + p * 16 + ln15] = acc[p][j];
}

extern "C" void kernel_launch(void* const* d_in, const int* in_sizes, int n_in,
                              void* d_out, int out_size, void* d_ws, size_t ws_size,
                              hipStream_t stream) {
    const float* x    = (const float*)d_in[0];
    const float* kc   = (const float*)d_in[1];
    const float* vc   = (const float*)d_in[2];
    const float* Wqkv = (const float*)d_in[3];
    const float* Wdw  = (const float*)d_in[4];
    const float* Wf1  = (const float*)d_in[5];
    const float* Wf2  = (const float*)d_in[6];
    const float* Wpr  = (const float*)d_in[7];
    const float* temp = (const float*)d_in[8];

    float* out   = (float*)d_out;
    float* k_out = out + OUT_N;            // (8,64,2,64,64)
    float* v_out = out + OUT_N + KV_N;

    float* ws   = (float*)d_ws;
    float* qkv  = ws;                      // [0 .. 4.19M floats) — dead after k2
    unsigned short* fb16 = (unsigned short*)ws;            // 6.29M shorts (reuses qkv region after k2)
    unsigned short* qbf = (unsigned short*)ws;             // 2M shorts (after fb16 dead)
    unsigned short* kbf = (unsigned short*)(ws + 1048576); // 2M shorts
    float* qbuf = ws + 6291456;            // 2,097,152
    float* kerb = ws + 8388608;            // 2,457,600
    float* kfil = ws + 10846208;           // 2,097,152
    float* vfil = ws + 12943360;           // 2,097,152
    unsigned short* wt1 = (unsigned short*)(ws + 15106048); // 36864 shorts
    unsigned short* wt2 = wt1 + 36864;                      // 18432 shorts
    float* attno= kerb;                    // alias: kerb free after k4b

    wprep   <<<27,    256, 0, stream>>>(Wf1, Wf2, wt1, wt2);
    k0_copy <<<4096,  256, 0, stream>>>((const float4*)kc, (const float4*)vc, k_out, v_out);
    k1_mfma <<<1024,  256, 0, stream>>>(x, Wqkv, qkv);
    k2_dw   <<<16384, 256, 0, stream>>>(qkv, Wdw, qbuf, k_out, v_out);
    k3_mfma1<<<dim3(32, 24), 256, 0, stream>>>(k_out, vc, wt1, fb16);
    k3b_mfma2<<<dim3(32, 24), 256, 0, stream>>>(fb16, wt2, kerb);
    k4b_apply<<<dim3(64, 8, 4), 256, 0, stream>>>(kerb, k_out, v_out, kfil, vfil);
    k4c_cvt <<<dim3(4, 128, 2), 256, 0, stream>>>(qbuf, kfil, qbf, kbf);
    k5_mfma <<<dim3(8, 128), 256, 0, stream>>>(qbf, kbf, vfil, temp, attno);
    k6_mfma <<<512,   256, 0, stream>>>(attno, Wpr, out);
}